// Round 3
// baseline (1701.869 us; speedup 1.0000x reference)
//
#include <hip/hip_runtime.h>
#include <cstdio>
#include <cstdint>

typedef __bf16 bf16_t;
typedef __bf16 bf16x8 __attribute__((ext_vector_type(8)));
typedef __bf16 bf16x4 __attribute__((ext_vector_type(4)));
typedef float  f32x4  __attribute__((ext_vector_type(4)));

// problem dims
#define B_ROWS 8192
#define GEN    5000
#define GENP   5120   // padded K for gemm1 / N for gemm_m (mult of 256)
#define H1     4128
#define H1P    4352   // mult of 256 (gemm256 N) and of 64 (K of gemm2/merger)
#define H2     2064
#define H2P    2176   // mult of 128 (gemm128 N)
#define LT     1032
#define LTP    1152   // mult of 64

// ---------------- async global->LDS helper ----------------
__device__ __forceinline__ void load_lds16(const bf16_t* g, bf16_t* l) {
  __builtin_amdgcn_global_load_lds((__attribute__((address_space(1))) void*)g,
                                   (__attribute__((address_space(3))) void*)l,
                                   16, 0, 0);
}

__device__ __forceinline__ int xcd_swizzle(int wg, int nwg) {
  const int q = nwg >> 3, r8 = nwg & 7;
  const int xcd = wg & 7, sidx = wg >> 3;
  return (xcd < r8 ? xcd * (q + 1) : r8 * (q + 1) + (xcd - r8) * q) + sidx;
}

// =======================================================================
// 256x256 8-wave phase-scheduled GEMM: C = A (MxK) * B^T (NxK)
// LDS: 2 buffers x (A 256x64 + B 256x64) bf16 = 128 KiB, granule-XOR swizzle.
// 4 phases per K-tile (BK=64), 16 MFMA/phase, setprio around MFMA,
// next-tile staging issued in phases 0-1, per-wave vmcnt drain at phase 3.
// MODE 0: bf16 C (ld Npad) + per-column sum/sumsq atomics.
// MODE 1: f32 C (ld Nvalid, col-bounded).
// =======================================================================
template<int MODE>
__global__ __launch_bounds__(512, 2)
void gemm256(const bf16_t* __restrict__ A, const bf16_t* __restrict__ Bm,
             int K, bf16_t* __restrict__ Cb, int Npad,
             float* __restrict__ sum, float* __restrict__ sq,
             float* __restrict__ Cf, int Nvalid)
{
  __shared__ bf16_t As[2][256 * 64];
  __shared__ bf16_t Bs[2][256 * 64];
  const int tid  = threadIdx.x;
  const int wave = tid >> 6;
  const int lane = tid & 63;

  int wg = xcd_swizzle((int)blockIdx.x + (int)blockIdx.y * gridDim.x,
                       gridDim.x * gridDim.y);
  const int brow = (wg / gridDim.x) * 256;
  const int bcol = (wg % gridDim.x) * 256;

  const int wm = wave >> 2;      // 0..1 -> 128-row half
  const int wn = wave & 3;       // 0..3 -> 64-col slice

  // staging: 8 threads per 64-elem row, 16B granule, XOR-swizzled source
  const int rr = tid >> 3;                        // 0..63
  const int cc = (((tid & 7) ^ (rr & 7)) << 3);
  const bf16_t* ga = A  + (size_t)(brow + rr) * K + cc;
  const bf16_t* gb = Bm + (size_t)(bcol + rr) * K + cc;

  auto stA = [&](int d, int i, long ko) {
    load_lds16(ga + (size_t)(i * 64) * K + ko, &As[d][(i * 64 + wave * 8) * 64]);
  };
  auto stB = [&](int d, int i, long ko) {
    load_lds16(gb + (size_t)(i * 64) * K + ko, &Bs[d][(i * 64 + wave * 8) * 64]);
  };

  f32x4 acc[8][4] = {};
  bf16x8 alo[4][2], ahi[4][2], blo[2][2], bhi[2][2];

  const int lr  = lane & 15;
  const int hi  = lane >> 4;
  const int rsw = lr & 7;
  const int arb = wm * 128 + lr;  // A row base (+ mf*16)
  const int bcb = wn * 64 + lr;   // B col base (+ nf*16)

#define RD_A(DST, MB, dd)                                                     \
  _Pragma("unroll") for (int mf = 0; mf < 4; ++mf)                            \
  _Pragma("unroll") for (int kk = 0; kk < 2; ++kk)                            \
    DST[mf][kk] = *(const bf16x8*)&As[dd][(arb + (MB) * 64 + mf * 16) * 64 +  \
                                          (((kk * 4 + hi) ^ rsw) << 3)];
#define RD_B(DST, NB, dd)                                                     \
  _Pragma("unroll") for (int nf = 0; nf < 2; ++nf)                            \
  _Pragma("unroll") for (int kk = 0; kk < 2; ++kk)                            \
    DST[nf][kk] = *(const bf16x8*)&Bs[dd][(bcb + (NB) * 16 + nf * 16) * 64 +  \
                                          (((kk * 4 + hi) ^ rsw) << 3)];
#define MFMA_Q(AF, BF, MB, NB)                                                \
  _Pragma("unroll") for (int mf = 0; mf < 4; ++mf)                            \
  _Pragma("unroll") for (int nf = 0; nf < 2; ++nf)                            \
  _Pragma("unroll") for (int kk = 0; kk < 2; ++kk)                            \
    acc[(MB) + mf][(NB) + nf] = __builtin_amdgcn_mfma_f32_16x16x32_bf16(      \
        AF[mf][kk], BF[nf][kk], acc[(MB) + mf][(NB) + nf], 0, 0, 0);

#define LGKM0 do { asm volatile("s_waitcnt lgkmcnt(0)" ::: "memory");         \
                   __builtin_amdgcn_sched_barrier(0); } while (0)
#define VMW0  asm volatile("s_waitcnt vmcnt(0)" ::: "memory")
#define BARR  __builtin_amdgcn_s_barrier()

  const int NT = K >> 6;

  // prologue: stage tile 0 fully
#pragma unroll
  for (int i = 0; i < 4; ++i) stA(0, i, 0);
#pragma unroll
  for (int i = 0; i < 4; ++i) stB(0, i, 0);
  VMW0;
  BARR;

  for (int T = 0; T < NT; ++T) {
    const int  d  = T & 1;
    const int  pd = d ^ 1;
    const long pk = (long)(T + 1) * 64;
    const bool pf = (T + 1 < NT);

    // ---- phase 0: read alo(8)+blo(4); stage A0,A1,B0,B1 of next tile
    RD_A(alo, 0, d);
    RD_B(blo, 0, d);
    if (pf) { stA(pd, 0, pk); stA(pd, 1, pk); stB(pd, 0, pk); stB(pd, 1, pk); }
    BARR;
    LGKM0;
    __builtin_amdgcn_s_setprio(1);
    MFMA_Q(alo, blo, 0, 0);
    __builtin_amdgcn_s_setprio(0);
    BARR;

    // ---- phase 1: read bhi(4); stage A2,A3,B2,B3 of next tile
    RD_B(bhi, 2, d);
    if (pf) { stA(pd, 2, pk); stA(pd, 3, pk); stB(pd, 2, pk); stB(pd, 3, pk); }
    BARR;
    LGKM0;
    __builtin_amdgcn_s_setprio(1);
    MFMA_Q(alo, bhi, 0, 2);
    __builtin_amdgcn_s_setprio(0);
    BARR;

    // ---- phase 2: read ahi(8)
    RD_A(ahi, 1, d);
    BARR;
    LGKM0;
    __builtin_amdgcn_s_setprio(1);
    MFMA_Q(ahi, bhi, 4, 2);
    __builtin_amdgcn_s_setprio(0);
    BARR;

    // ---- phase 3: no reads (ahi, blo live); drain this wave's prefetch loads
    __builtin_amdgcn_s_setprio(1);
    MFMA_Q(ahi, blo, 4, 0);
    __builtin_amdgcn_s_setprio(0);
    VMW0;
    BARR;
  }

  // epilogue: C/D layout col=lane&15, row=(lane>>4)*4+reg
  if (MODE == 0) {
#pragma unroll
    for (int nf = 0; nf < 4; ++nf) {
      const int colg = bcol + wn * 64 + nf * 16 + lr;
      float s = 0.f, s2 = 0.f;
#pragma unroll
      for (int mf = 0; mf < 8; ++mf) {
        const int rowg = brow + wm * 128 + mf * 16 + hi * 4;
#pragma unroll
        for (int r = 0; r < 4; ++r) {
          float v = acc[mf][nf][r];
          s += v; s2 += v * v;
          Cb[(size_t)(rowg + r) * Npad + colg] = (bf16_t)v;
        }
      }
      s  += __shfl_xor(s, 16, 64);  s  += __shfl_xor(s, 32, 64);
      s2 += __shfl_xor(s2, 16, 64); s2 += __shfl_xor(s2, 32, 64);
      if (lane < 16) {
        atomicAdd(&sum[colg], s);
        atomicAdd(&sq[colg], s2);
      }
    }
  } else {
#pragma unroll
    for (int nf = 0; nf < 4; ++nf) {
      const int colg = bcol + wn * 64 + nf * 16 + lr;
      if (colg < Nvalid) {
#pragma unroll
        for (int mf = 0; mf < 8; ++mf) {
          const int rowg = brow + wm * 128 + mf * 16 + hi * 4;
#pragma unroll
          for (int r = 0; r < 4; ++r)
            Cf[(size_t)(rowg + r) * Nvalid + colg] = acc[mf][nf][r];
        }
      }
    }
  }
#undef RD_A
#undef RD_B
#undef MFMA_Q
#undef LGKM0
#undef VMW0
#undef BARR
}

// =======================================================================
// 128x128 4-wave GEMM (r2 structure) — for the smaller GEMMs
// =======================================================================
template<int MODE>
__global__ __launch_bounds__(256, 2)
void gemm_bt(const bf16_t* __restrict__ A, const bf16_t* __restrict__ Bm,
             int K, bf16_t* __restrict__ Cb, int Npad,
             float* __restrict__ sum, float* __restrict__ sq,
             float* __restrict__ Cf, int Nvalid)
{
  __shared__ bf16_t As[128 * 64];
  __shared__ bf16_t Bs[128 * 64];
  const int tid  = threadIdx.x;
  const int wave = tid >> 6;
  const int lane = tid & 63;

  int wg = xcd_swizzle((int)blockIdx.x + (int)blockIdx.y * gridDim.x,
                       gridDim.x * gridDim.y);
  const int brow = (wg / gridDim.x) * 128;
  const int bcol = (wg % gridDim.x) * 128;

  const int wrow = (wave >> 1) * 64;
  const int wcol = (wave & 1) * 64;

  const int rr  = tid >> 3;                         // 0..31
  const int cc  = (((tid & 7) ^ (rr & 7)) << 3);    // swizzled 8-elem granule

  const bf16_t* ga[4];
  const bf16_t* gb[4];
#pragma unroll
  for (int i = 0; i < 4; ++i) {
    ga[i] = A  + (size_t)(brow + i * 32 + rr) * K + cc;
    gb[i] = Bm + (size_t)(bcol + i * 32 + rr) * K + cc;
  }
  bf16_t* lab = As + wave * 512;
  bf16_t* lbb = Bs + wave * 512;

  f32x4 acc[4][4] = {};

  const int lr  = lane & 15;
  const int g0  = lane >> 4;
  const int rsw = lr & 7;

  for (int kt = 0; kt < K; kt += 64) {
#pragma unroll
    for (int i = 0; i < 4; ++i) {
      load_lds16(ga[i] + kt, lab + i * 2048);
      load_lds16(gb[i] + kt, lbb + i * 2048);
    }
    __syncthreads();
#pragma unroll
    for (int kk = 0; kk < 2; ++kk) {
      const int swz = (((kk * 4 + g0) ^ rsw) << 3);
      bf16x8 af[4], bfr[4];
#pragma unroll
      for (int mi = 0; mi < 4; ++mi)
        af[mi] = *(const bf16x8*)(As + (wrow + mi * 16 + lr) * 64 + swz);
#pragma unroll
      for (int ni = 0; ni < 4; ++ni)
        bfr[ni] = *(const bf16x8*)(Bs + (wcol + ni * 16 + lr) * 64 + swz);
#pragma unroll
      for (int mi = 0; mi < 4; ++mi)
#pragma unroll
        for (int ni = 0; ni < 4; ++ni)
          acc[mi][ni] = __builtin_amdgcn_mfma_f32_16x16x32_bf16(af[mi], bfr[ni], acc[mi][ni], 0, 0, 0);
    }
    __syncthreads();
  }

  const int lcol = lane & 15;
  const int lrow = (lane >> 4) * 4;
  if (MODE == 0) {
#pragma unroll
    for (int ni = 0; ni < 4; ++ni) {
      const int colg = bcol + wcol + ni * 16 + lcol;
      float s = 0.f, s2 = 0.f;
#pragma unroll
      for (int mi = 0; mi < 4; ++mi) {
        const int rowg = brow + wrow + mi * 16 + lrow;
#pragma unroll
        for (int r = 0; r < 4; ++r) {
          float v = acc[mi][ni][r];
          s += v; s2 += v * v;
          Cb[(size_t)(rowg + r) * Npad + colg] = (bf16_t)v;
        }
      }
      s  += __shfl_xor(s, 16, 64);  s  += __shfl_xor(s, 32, 64);
      s2 += __shfl_xor(s2, 16, 64); s2 += __shfl_xor(s2, 32, 64);
      if (lane < 16) {
        atomicAdd(&sum[colg], s);
        atomicAdd(&sq[colg], s2);
      }
    }
  } else {
#pragma unroll
    for (int ni = 0; ni < 4; ++ni) {
      const int colg = bcol + wcol + ni * 16 + lcol;
      if (colg < Nvalid) {
#pragma unroll
        for (int mi = 0; mi < 4; ++mi) {
          const int rowg = brow + wrow + mi * 16 + lrow;
#pragma unroll
          for (int r = 0; r < 4; ++r)
            Cf[(size_t)(rowg + r) * Nvalid + colg] = acc[mi][ni][r];
        }
      }
    }
  }
}

// ---------------- prep: out[npad][kpad] = bf16(W*mask), zero-padded ----------------
__global__ void k_prep(const float* __restrict__ W, const float* __restrict__ Mk,
                       bf16_t* __restrict__ out, int N, int K, int Npad, int Kpad)
{
  const int  kg    = Kpad >> 3;
  const long total = (long)Npad * kg;
  for (long idx = (long)blockIdx.x * blockDim.x + threadIdx.x; idx < total;
       idx += (long)gridDim.x * blockDim.x) {
    const int n = (int)(idx / kg);
    const int c = (int)(idx % kg) * 8;
    bf16x8 o;
#pragma unroll
    for (int j = 0; j < 8; ++j) o[j] = (bf16_t)0.f;
    if (n < N && c < K) {               // K % 8 == 0 for all inputs
      const f32x4* w4 = (const f32x4*)(W + (size_t)n * K + c);
      f32x4 a = w4[0], b = w4[1];
      if (Mk) {
        const f32x4* m4 = (const f32x4*)(Mk + (size_t)n * K + c);
        f32x4 ma = m4[0], mb = m4[1];
        a *= ma; b *= mb;
      }
#pragma unroll
      for (int j = 0; j < 4; ++j) { o[j] = (bf16_t)a[j]; o[4 + j] = (bf16_t)b[j]; }
    }
    *(bf16x8*)(out + (size_t)idx * 8) = o;
  }
}

// ---------------- BN finalize: sum->scale, sq->shift ----------------
__global__ void k_finalize(float* __restrict__ sum, float* __restrict__ sq,
                           const float* __restrict__ g, const float* __restrict__ be,
                           int Nvalid, int Npad)
{
  const int c = blockIdx.x * blockDim.x + threadIdx.x;
  if (c >= Npad) return;
  float sc = 0.f, sh = 0.f;
  if (c < Nvalid) {
    const float invM = 1.0f / 8192.0f;
    float mean = sum[c] * invM;
    float var  = sq[c] * invM - mean * mean;
    sc = g[c] * rsqrtf(var + 1e-3f);
    sh = be[c] - mean * sc;
  }
  sum[c] = sc; sq[c] = sh;
}

// ---------------- BN apply (+optional ELU, optional f32 out) ----------------
__global__ void k_bn_elu(const bf16_t* __restrict__ pre, const float* __restrict__ sc,
                         const float* __restrict__ sh, bf16_t* __restrict__ outb,
                         float* __restrict__ outf, int Nvalid, int Npad, int elu)
{
  const int  ng    = Npad >> 3;
  const long total = (long)B_ROWS * ng;
  for (long idx = (long)blockIdx.x * blockDim.x + threadIdx.x; idx < total;
       idx += (long)gridDim.x * blockDim.x) {
    const int r = (int)(idx / ng);
    const int c = (int)(idx % ng) * 8;
    bf16x8 o;
#pragma unroll
    for (int j = 0; j < 8; ++j) o[j] = (bf16_t)0.f;
    if (c < Nvalid) {                   // Nvalid % 8 == 0 -> group fully valid
      bf16x8 x = *(const bf16x8*)(pre + (size_t)r * Npad + c);
      f32x4 y0, y1;
#pragma unroll
      for (int j = 0; j < 8; ++j) {
        float v = (float)x[j] * sc[c + j] + sh[c + j];
        if (elu) v = v > 0.f ? v : expm1f(v);
        if (j < 4) y0[j] = v; else y1[j - 4] = v;
        o[j] = (bf16_t)v;
      }
      if (outf) {
        float* p = outf + (size_t)r * Nvalid + c;
        *(f32x4*)p       = y0;
        *(f32x4*)(p + 4) = y1;
      }
    }
    *(bf16x8*)(outb + (size_t)r * Npad + c) = o;
  }
}

// ---------------- reparametrize: mu/logvar/z f32 out + z bf16 (padded) ----------------
__global__ void k_reparam(const bf16_t* __restrict__ p, const float* __restrict__ sc,
                          const float* __restrict__ sh, const float* __restrict__ eps,
                          float* __restrict__ z, float* __restrict__ mu,
                          float* __restrict__ lv, bf16_t* __restrict__ zb)
{
  const long total = (long)B_ROWS * (LTP / 4);
  for (long idx = (long)blockIdx.x * blockDim.x + threadIdx.x; idx < total;
       idx += (long)gridDim.x * blockDim.x) {
    const int r = (int)(idx / (LTP / 4));
    const int j = (int)(idx % (LTP / 4)) * 4;
    if (j < LT) {                       // LT % 4 == 0
      bf16x4 pm = *(const bf16x4*)(p + (size_t)r * H2P + j);
      bf16x4 pl = *(const bf16x4*)(p + (size_t)r * H2P + LT + j);
      f32x4  e  = *(const f32x4*)(eps + (size_t)r * LT + j);
      f32x4 mv, lvv, zv; bf16x4 z4;
#pragma unroll
      for (int t = 0; t < 4; ++t) {
        float m_ = (float)pm[t] * sc[j + t] + sh[j + t];
        float l_ = (float)pl[t] * sc[LT + j + t] + sh[LT + j + t];
        float zz = fmaf(expf(l_ * 0.5f), e[t], m_);
        mv[t] = m_; lvv[t] = l_; zv[t] = zz; z4[t] = (bf16_t)zz;
      }
      *(f32x4*)(mu + (size_t)r * LT + j) = mv;
      *(f32x4*)(lv + (size_t)r * LT + j) = lvv;
      *(f32x4*)(z  + (size_t)r * LT + j) = zv;
      *(bf16x4*)(zb + (size_t)r * LTP + j) = z4;
    } else {
      bf16x4 z4;
#pragma unroll
      for (int t = 0; t < 4; ++t) z4[t] = (bf16_t)0.f;
      *(bf16x4*)(zb + (size_t)r * LTP + j) = z4;
    }
  }
}

// ---------------- host ----------------
extern "C" void kernel_launch(void* const* d_in, const int* in_sizes, int n_in,
                              void* d_out, int out_size, void* d_ws, size_t ws_size,
                              hipStream_t stream)
{
  const float* x     = (const float*)d_in[0];
  const float* eps   = (const float*)d_in[1];
  const float* mask1 = (const float*)d_in[2];
  const float* mask2 = (const float*)d_in[3];
  const float* maskd = (const float*)d_in[4];
  const float* maskm = (const float*)d_in[5];
  const float* W1    = (const float*)d_in[6];
  // b1 (d_in[7]) cancels in BN (mean subtraction) -> unused
  const float* g1    = (const float*)d_in[8];
  const float* be1   = (const float*)d_in[9];
  const float* W2    = (const float*)d_in[10];
  // b2 (d_in[11]) cancels in BN
  const float* g2    = (const float*)d_in[12];
  const float* be2   = (const float*)d_in[13];
  const float* Wd    = (const float*)d_in[14];
  // bd (d_in[15]) cancels in BN
  const float* gd    = (const float*)d_in[16];
  const float* bed   = (const float*)d_in[17];
  const float* Wm    = (const float*)d_in[18];
  float* out = (float*)d_out;
  char*  ws  = (char*)d_ws;

  // workspace layout (aliased where lifetimes are disjoint)
  size_t off = 0;
  auto alloc = [&](size_t bytes) { size_t o = off; off += (bytes + 255) & ~(size_t)255; return o; };
  const size_t XBF  = alloc((size_t)B_ROWS * GENP * 2);  // x bf16; later mo_bf16
  const size_t W1M  = alloc((size_t)H1P * GENP * 2);     // W1 masked; later p_pre
  const size_t W2M  = alloc((size_t)H2P * H1P * 2);
  const size_t WDM  = alloc((size_t)H1P * LTP * 2);
  const size_t WMM  = alloc((size_t)GENP * H1P * 2);
  const size_t HPRE = alloc((size_t)B_ROWS * H1P * 2);   // h_pre; later d_pre
  const size_t HBF  = alloc((size_t)B_ROWS * H1P * 2);   // h bf16; later z bf16
  const size_t STAT = alloc((size_t)(H1P + H2P + H1P) * 2 * sizeof(float));
  if (ws_size < off) {
    fprintf(stderr, "kernel_launch: workspace too small: need %zu have %zu\n", off, ws_size);
    return;
  }

  bf16_t* xb   = (bf16_t*)(ws + XBF);
  bf16_t* w1m  = (bf16_t*)(ws + W1M);
  bf16_t* w2m  = (bf16_t*)(ws + W2M);
  bf16_t* wdm  = (bf16_t*)(ws + WDM);
  bf16_t* wmm  = (bf16_t*)(ws + WMM);
  bf16_t* hpre = (bf16_t*)(ws + HPRE);
  bf16_t* hbf  = (bf16_t*)(ws + HBF);
  bf16_t* ppre = (bf16_t*)(ws + W1M);   // alias: W1 masked dead after GEMM1
  bf16_t* zbf  = (bf16_t*)(ws + HBF);   // alias: h bf16 dead after GEMM2
  bf16_t* dpre = (bf16_t*)(ws + HPRE);  // alias: h_pre dead after BN1 apply
  bf16_t* mobf = (bf16_t*)(ws + XBF);   // alias: x bf16 dead after GEMM1

  float* s1 = (float*)(ws + STAT);
  float* q1 = s1 + H1P;
  float* s2 = q1 + H1P;
  float* q2 = s2 + H2P;
  float* sd = q2 + H2P;
  float* qd = sd + H1P;

  float* o_recon = out;
  float* o_z     = o_recon + (size_t)B_ROWS * GEN;
  float* o_mo    = o_z     + (size_t)B_ROWS * LT;
  float* o_mu    = o_mo    + (size_t)B_ROWS * H1;
  float* o_lv    = o_mu    + (size_t)B_ROWS * LT;

  hipMemsetAsync(ws + STAT, 0, (size_t)(H1P + H2P + H1P) * 2 * sizeof(float), stream);

  // prep: cast/mask to bf16, zero-padded
  k_prep<<<2048, 256, 0, stream>>>(x,  nullptr, xb,  B_ROWS, GEN, B_ROWS, GENP);
  k_prep<<<2048, 256, 0, stream>>>(W1, mask1,   w1m, H1,  GEN, H1P,  GENP);
  k_prep<<<2048, 256, 0, stream>>>(W2, mask2,   w2m, H2,  H1,  H2P,  H1P);
  k_prep<<<2048, 256, 0, stream>>>(Wd, maskd,   wdm, H1,  LT,  H1P,  LTP);
  k_prep<<<2048, 256, 0, stream>>>(Wm, maskm,   wmm, GEN, H1,  GENP, H1P);

  // encoder L1: h_pre = x @ W1m^T  (+ batch stats)  [256^2 8-phase]
  gemm256<0><<<dim3(H1P / 256, B_ROWS / 256), 512, 0, stream>>>(
      xb, w1m, GENP, hpre, H1P, s1, q1, nullptr, 0);
  k_finalize<<<(H1P + 255) / 256, 256, 0, stream>>>(s1, q1, g1, be1, H1, H1P);
  k_bn_elu<<<2048, 256, 0, stream>>>(hpre, s1, q1, hbf, nullptr, H1, H1P, 1);

  // encoder L2: p_pre = h @ W2m^T (+ stats), then reparametrize  [128^2]
  gemm_bt<0><<<dim3(H2P / 128, B_ROWS / 128), 256, 0, stream>>>(
      hbf, w2m, H1P, ppre, H2P, s2, q2, nullptr, 0);
  k_finalize<<<(H2P + 255) / 256, 256, 0, stream>>>(s2, q2, g2, be2, H2, H2P);
  k_reparam<<<2048, 256, 0, stream>>>(ppre, s2, q2, eps, o_z, o_mu, o_lv, zbf);

  // decoder: d_pre = z @ Wdm^T (+ stats), BN+ELU -> module_outputs  [128^2]
  gemm_bt<0><<<dim3(H1P / 128, B_ROWS / 128), 256, 0, stream>>>(
      zbf, wdm, LTP, dpre, H1P, sd, qd, nullptr, 0);
  k_finalize<<<(H1P + 255) / 256, 256, 0, stream>>>(sd, qd, gd, bed, H1, H1P);
  k_bn_elu<<<2048, 256, 0, stream>>>(dpre, sd, qd, mobf, o_mo, H1, H1P, 1);

  // merger: global_recon = mo @ Wmm^T (f32 out, no BN)  [256^2 8-phase]
  gemm256<1><<<dim3(GENP / 256, B_ROWS / 256), 512, 0, stream>>>(
      mobf, wmm, H1P, nullptr, 0, nullptr, nullptr, o_recon, GEN);
}

// Round 4
// 1601.973 us; speedup vs baseline: 1.0624x; 1.0624x over previous
//
#include <hip/hip_runtime.h>
#include <cstdio>
#include <cstdint>

typedef __bf16 bf16_t;
typedef __bf16 bf16x8 __attribute__((ext_vector_type(8)));
typedef __bf16 bf16x4 __attribute__((ext_vector_type(4)));
typedef float  f32x4  __attribute__((ext_vector_type(4)));

// problem dims
#define B_ROWS 8192
#define GEN    5000
#define GENP   5120   // padded K for gemm1 / N for gemm_m (mult of 256; K/64 even)
#define H1     4128
#define H1P    4352   // mult of 256 (gemm256 N), K/64 even for merger
#define H2     2064
#define H2P    2176   // mult of 128 (gemm128 N)
#define LT     1032
#define LTP    1152   // mult of 64

// ---------------- async global->LDS helper ----------------
__device__ __forceinline__ void load_lds16(const bf16_t* g, bf16_t* l) {
  __builtin_amdgcn_global_load_lds((__attribute__((address_space(1))) void*)g,
                                   (__attribute__((address_space(3))) void*)l,
                                   16, 0, 0);
}

__device__ __forceinline__ int xcd_swizzle(int wg, int nwg) {
  const int q = nwg >> 3, r8 = nwg & 7;
  const int xcd = wg & 7, sidx = wg >> 3;
  return (xcd < r8 ? xcd * (q + 1) : r8 * (q + 1) + (xcd - r8) * q) + sidx;
}

// =======================================================================
// 256x256 8-wave 8-phase GEMM with COUNTED vmcnt (T3+T4+T5), BK=64.
// 2 K-tiles per iteration: tile T (even) in buf0, T+1 in buf1.
// Rolling staging, 2 global_load_lds per phase:
//   P1/P2: A[T+1]->buf1   P3/P4: B[T+2]->buf0
//   P5/P6: A[T+2]->buf0   P7/P8: B[T+3]->buf1
// vmcnt(4) ONLY at end-P4 and end-P8 (drain-to-0 only in last iteration).
// Requires K/64 even. Granule-XOR LDS swizzle (source-side, linear dest).
// MODE 0: bf16 C (ld Npad) + per-column sum/sumsq atomics.
// MODE 1: f32 C (ld Nvalid, col-bounded).
// =======================================================================
template<int MODE>
__global__ __launch_bounds__(512, 2)
void gemm256(const bf16_t* __restrict__ A, const bf16_t* __restrict__ Bm,
             int K, bf16_t* __restrict__ Cb, int Npad,
             float* __restrict__ sum, float* __restrict__ sq,
             float* __restrict__ Cf, int Nvalid)
{
  __shared__ bf16_t As[2][256 * 64];
  __shared__ bf16_t Bs[2][256 * 64];
  const int tid  = threadIdx.x;
  const int wave = tid >> 6;
  const int lane = tid & 63;

  int wg = xcd_swizzle((int)blockIdx.x + (int)blockIdx.y * gridDim.x,
                       gridDim.x * gridDim.y);
  const int brow = (wg / gridDim.x) * 256;
  const int bcol = (wg % gridDim.x) * 256;

  const int wm = wave >> 2;      // 0..1 -> 128-row half
  const int wn = wave & 3;       // 0..3 -> 64-col slice

  // staging: 8 threads per 64-elem row, 16B granule, XOR-swizzled source
  const int rr = tid >> 3;                        // 0..63
  const int cc = (((tid & 7) ^ (rr & 7)) << 3);
  const bf16_t* ga = A  + (size_t)(brow + rr) * K + cc;
  const bf16_t* gb = Bm + (size_t)(bcol + rr) * K + cc;

  // stage granule i (64 rows) of tile at column-offset ko into buffer d
  auto stA = [&](int d, int i, long ko) {
    load_lds16(ga + (size_t)(i * 64) * K + ko, &As[d][(i * 64 + wave * 8) * 64]);
  };
  auto stB = [&](int d, int i, long ko) {
    load_lds16(gb + (size_t)(i * 64) * K + ko, &Bs[d][(i * 64 + wave * 8) * 64]);
  };

  f32x4 acc[8][4] = {};
  bf16x8 alo[4][2], ahi[4][2], blo[2][2], bhi[2][2];

  const int lr  = lane & 15;
  const int hi  = lane >> 4;
  const int rsw = lr & 7;
  const int arb = wm * 128 + lr;  // A row base (+ mf*16)
  const int bcb = wn * 64 + lr;   // B col base (+ nf*16)

#define RD_A(DST, MB, dd)                                                     \
  _Pragma("unroll") for (int mf = 0; mf < 4; ++mf)                            \
  _Pragma("unroll") for (int kk = 0; kk < 2; ++kk)                            \
    DST[mf][kk] = *(const bf16x8*)&As[dd][(arb + (MB) * 64 + mf * 16) * 64 +  \
                                          (((kk * 4 + hi) ^ rsw) << 3)];
#define RD_B(DST, NB, dd)                                                     \
  _Pragma("unroll") for (int nf = 0; nf < 2; ++nf)                            \
  _Pragma("unroll") for (int kk = 0; kk < 2; ++kk)                            \
    DST[nf][kk] = *(const bf16x8*)&Bs[dd][(bcb + (NB) * 16 + nf * 16) * 64 +  \
                                          (((kk * 4 + hi) ^ rsw) << 3)];
#define MFMA_Q(AF, BF, MB, NB)                                                \
  _Pragma("unroll") for (int mf = 0; mf < 4; ++mf)                            \
  _Pragma("unroll") for (int nf = 0; nf < 2; ++nf)                            \
  _Pragma("unroll") for (int kk = 0; kk < 2; ++kk)                            \
    acc[(MB) + mf][(NB) + nf] = __builtin_amdgcn_mfma_f32_16x16x32_bf16(      \
        AF[mf][kk], BF[nf][kk], acc[(MB) + mf][(NB) + nf], 0, 0, 0);

#define LGKM0 do { asm volatile("s_waitcnt lgkmcnt(0)" ::: "memory");         \
                   __builtin_amdgcn_sched_barrier(0); } while (0)
#define VMW(N) asm volatile("s_waitcnt vmcnt(" #N ")" ::: "memory")
#define BARR  __builtin_amdgcn_s_barrier()
#define PRIO1 __builtin_amdgcn_s_setprio(1)
#define PRIO0 __builtin_amdgcn_s_setprio(0)

  const int NT = K >> 6;          // even by construction

  // ---- prologue: A[0],B[0] -> buf0; B[1] -> buf1; allow B[1] in flight
  stA(0, 0, 0); stA(0, 1, 0); stA(0, 2, 0); stA(0, 3, 0);
  stB(0, 0, 0); stB(0, 1, 0); stB(0, 2, 0); stB(0, 3, 0);
  stB(1, 0, 64); stB(1, 1, 64); stB(1, 2, 64); stB(1, 3, 64);
  VMW(4);
  BARR;

  for (int it = 0; it < (NT >> 1); ++it) {
    const int  T   = it * 2;
    const long k1  = (long)(T + 1) * 64;
    const long k2  = (long)(T + 2) * 64;
    const long k3  = (long)(T + 3) * 64;
    const bool pf2 = (T + 2 < NT);
    const bool pf3 = (T + 3 < NT);

    // P1: Q0(T) = alo·blo ; stage A[T+1] g0,g2 -> buf1
    RD_A(alo, 0, 0); RD_B(blo, 0, 0);
    stA(1, 0, k1); stA(1, 2, k1);
    BARR; LGKM0; PRIO1; MFMA_Q(alo, blo, 0, 0); PRIO0; BARR;

    // P2: Q1(T) = alo·bhi ; stage A[T+1] g1,g3 -> buf1
    RD_B(bhi, 2, 0);
    stA(1, 1, k1); stA(1, 3, k1);
    BARR; LGKM0; PRIO1; MFMA_Q(alo, bhi, 0, 2); PRIO0; BARR;

    // P3: Q2(T) = ahi·bhi ; stage B[T+2] g0,g1 -> buf0 (B[T] reads done @P2)
    RD_A(ahi, 1, 0);
    if (pf2) { stB(0, 0, k2); stB(0, 1, k2); }
    BARR; LGKM0; PRIO1; MFMA_Q(ahi, bhi, 4, 2); PRIO0; BARR;

    // P4: Q3(T) = ahi·blo (regs held) ; stage B[T+2] g2,g3 ; WAIT-1
    if (pf2) { stB(0, 2, k2); stB(0, 3, k2); }
    PRIO1; MFMA_Q(ahi, blo, 4, 0); PRIO0;
    if (pf2) { VMW(4); } else { VMW(0); }   // complete thru P2 (A[T+1], B[T+1])
    BARR;

    // P5: Q0(T+1) ; stage A[T+2] g0,g2 -> buf0 (A[T] reads done @P3)
    RD_A(alo, 0, 1); RD_B(blo, 0, 1);
    if (pf2) { stA(0, 0, k2); stA(0, 2, k2); }
    BARR; LGKM0; PRIO1; MFMA_Q(alo, blo, 0, 0); PRIO0; BARR;

    // P6: Q1(T+1) ; stage A[T+2] g1,g3 -> buf0
    RD_B(bhi, 2, 1);
    if (pf2) { stA(0, 1, k2); stA(0, 3, k2); }
    BARR; LGKM0; PRIO1; MFMA_Q(alo, bhi, 0, 2); PRIO0; BARR;

    // P7: Q2(T+1) ; stage B[T+3] g0,g1 -> buf1 (B[T+1] reads done @P6)
    RD_A(ahi, 1, 1);
    if (pf3) { stB(1, 0, k3); stB(1, 1, k3); }
    BARR; LGKM0; PRIO1; MFMA_Q(ahi, bhi, 4, 2); PRIO0; BARR;

    // P8: Q3(T+1) ; stage B[T+3] g2,g3 ; WAIT-2 (complete thru P6)
    if (pf3) { stB(1, 2, k3); stB(1, 3, k3); }
    PRIO1; MFMA_Q(ahi, blo, 4, 0); PRIO0;
    if (pf2) { VMW(4); BARR; }              // last iter: no next reads, skip
  }

  // epilogue: C/D layout col=lane&15, row=(lane>>4)*4+reg
  if (MODE == 0) {
#pragma unroll
    for (int nf = 0; nf < 4; ++nf) {
      const int colg = bcol + wn * 64 + nf * 16 + lr;
      float s = 0.f, s2 = 0.f;
#pragma unroll
      for (int mf = 0; mf < 8; ++mf) {
        const int rowg = brow + wm * 128 + mf * 16 + hi * 4;
#pragma unroll
        for (int r = 0; r < 4; ++r) {
          float v = acc[mf][nf][r];
          s += v; s2 += v * v;
          Cb[(size_t)(rowg + r) * Npad + colg] = (bf16_t)v;
        }
      }
      s  += __shfl_xor(s, 16, 64);  s  += __shfl_xor(s, 32, 64);
      s2 += __shfl_xor(s2, 16, 64); s2 += __shfl_xor(s2, 32, 64);
      if (lane < 16) {
        atomicAdd(&sum[colg], s);
        atomicAdd(&sq[colg], s2);
      }
    }
  } else {
#pragma unroll
    for (int nf = 0; nf < 4; ++nf) {
      const int colg = bcol + wn * 64 + nf * 16 + lr;
      if (colg < Nvalid) {
#pragma unroll
        for (int mf = 0; mf < 8; ++mf) {
          const int rowg = brow + wm * 128 + mf * 16 + hi * 4;
#pragma unroll
          for (int r = 0; r < 4; ++r)
            Cf[(size_t)(rowg + r) * Nvalid + colg] = acc[mf][nf][r];
        }
      }
    }
  }
#undef RD_A
#undef RD_B
#undef MFMA_Q
#undef LGKM0
#undef VMW
#undef BARR
#undef PRIO1
#undef PRIO0
}

// =======================================================================
// 128x128 4-wave GEMM (r2 structure) — for the smaller GEMMs
// =======================================================================
template<int MODE>
__global__ __launch_bounds__(256, 2)
void gemm_bt(const bf16_t* __restrict__ A, const bf16_t* __restrict__ Bm,
             int K, bf16_t* __restrict__ Cb, int Npad,
             float* __restrict__ sum, float* __restrict__ sq,
             float* __restrict__ Cf, int Nvalid)
{
  __shared__ bf16_t As[128 * 64];
  __shared__ bf16_t Bs[128 * 64];
  const int tid  = threadIdx.x;
  const int wave = tid >> 6;
  const int lane = tid & 63;

  int wg = xcd_swizzle((int)blockIdx.x + (int)blockIdx.y * gridDim.x,
                       gridDim.x * gridDim.y);
  const int brow = (wg / gridDim.x) * 128;
  const int bcol = (wg % gridDim.x) * 128;

  const int wrow = (wave >> 1) * 64;
  const int wcol = (wave & 1) * 64;

  const int rr  = tid >> 3;                         // 0..31
  const int cc  = (((tid & 7) ^ (rr & 7)) << 3);    // swizzled 8-elem granule

  const bf16_t* ga[4];
  const bf16_t* gb[4];
#pragma unroll
  for (int i = 0; i < 4; ++i) {
    ga[i] = A  + (size_t)(brow + i * 32 + rr) * K + cc;
    gb[i] = Bm + (size_t)(bcol + i * 32 + rr) * K + cc;
  }
  bf16_t* lab = As + wave * 512;
  bf16_t* lbb = Bs + wave * 512;

  f32x4 acc[4][4] = {};

  const int lr  = lane & 15;
  const int g0  = lane >> 4;
  const int rsw = lr & 7;

  for (int kt = 0; kt < K; kt += 64) {
#pragma unroll
    for (int i = 0; i < 4; ++i) {
      load_lds16(ga[i] + kt, lab + i * 2048);
      load_lds16(gb[i] + kt, lbb + i * 2048);
    }
    __syncthreads();
#pragma unroll
    for (int kk = 0; kk < 2; ++kk) {
      const int swz = (((kk * 4 + g0) ^ rsw) << 3);
      bf16x8 af[4], bfr[4];
#pragma unroll
      for (int mi = 0; mi < 4; ++mi)
        af[mi] = *(const bf16x8*)(As + (wrow + mi * 16 + lr) * 64 + swz);
#pragma unroll
      for (int ni = 0; ni < 4; ++ni)
        bfr[ni] = *(const bf16x8*)(Bs + (wcol + ni * 16 + lr) * 64 + swz);
#pragma unroll
      for (int mi = 0; mi < 4; ++mi)
#pragma unroll
        for (int ni = 0; ni < 4; ++ni)
          acc[mi][ni] = __builtin_amdgcn_mfma_f32_16x16x32_bf16(af[mi], bfr[ni], acc[mi][ni], 0, 0, 0);
    }
    __syncthreads();
  }

  const int lcol = lane & 15;
  const int lrow = (lane >> 4) * 4;
  if (MODE == 0) {
#pragma unroll
    for (int ni = 0; ni < 4; ++ni) {
      const int colg = bcol + wcol + ni * 16 + lcol;
      float s = 0.f, s2 = 0.f;
#pragma unroll
      for (int mi = 0; mi < 4; ++mi) {
        const int rowg = brow + wrow + mi * 16 + lrow;
#pragma unroll
        for (int r = 0; r < 4; ++r) {
          float v = acc[mi][ni][r];
          s += v; s2 += v * v;
          Cb[(size_t)(rowg + r) * Npad + colg] = (bf16_t)v;
        }
      }
      s  += __shfl_xor(s, 16, 64);  s  += __shfl_xor(s, 32, 64);
      s2 += __shfl_xor(s2, 16, 64); s2 += __shfl_xor(s2, 32, 64);
      if (lane < 16) {
        atomicAdd(&sum[colg], s);
        atomicAdd(&sq[colg], s2);
      }
    }
  } else {
#pragma unroll
    for (int ni = 0; ni < 4; ++ni) {
      const int colg = bcol + wcol + ni * 16 + lcol;
      if (colg < Nvalid) {
#pragma unroll
        for (int mi = 0; mi < 4; ++mi) {
          const int rowg = brow + wrow + mi * 16 + lrow;
#pragma unroll
          for (int r = 0; r < 4; ++r)
            Cf[(size_t)(rowg + r) * Nvalid + colg] = acc[mi][ni][r];
        }
      }
    }
  }
}

// ---------------- prep: out[npad][kpad] = bf16(W*mask), zero-padded ----------------
__global__ void k_prep(const float* __restrict__ W, const float* __restrict__ Mk,
                       bf16_t* __restrict__ out, int N, int K, int Npad, int Kpad)
{
  const int  kg    = Kpad >> 3;
  const long total = (long)Npad * kg;
  for (long idx = (long)blockIdx.x * blockDim.x + threadIdx.x; idx < total;
       idx += (long)gridDim.x * blockDim.x) {
    const int n = (int)(idx / kg);
    const int c = (int)(idx % kg) * 8;
    bf16x8 o;
#pragma unroll
    for (int j = 0; j < 8; ++j) o[j] = (bf16_t)0.f;
    if (n < N && c < K) {               // K % 8 == 0 for all inputs
      const f32x4* w4 = (const f32x4*)(W + (size_t)n * K + c);
      f32x4 a = w4[0], b = w4[1];
      if (Mk) {
        const f32x4* m4 = (const f32x4*)(Mk + (size_t)n * K + c);
        f32x4 ma = m4[0], mb = m4[1];
        a *= ma; b *= mb;
      }
#pragma unroll
      for (int j = 0; j < 4; ++j) { o[j] = (bf16_t)a[j]; o[4 + j] = (bf16_t)b[j]; }
    }
    *(bf16x8*)(out + (size_t)idx * 8) = o;
  }
}

// ---------------- BN finalize: sum->scale, sq->shift ----------------
__global__ void k_finalize(float* __restrict__ sum, float* __restrict__ sq,
                           const float* __restrict__ g, const float* __restrict__ be,
                           int Nvalid, int Npad)
{
  const int c = blockIdx.x * blockDim.x + threadIdx.x;
  if (c >= Npad) return;
  float sc = 0.f, sh = 0.f;
  if (c < Nvalid) {
    const float invM = 1.0f / 8192.0f;
    float mean = sum[c] * invM;
    float var  = sq[c] * invM - mean * mean;
    sc = g[c] * rsqrtf(var + 1e-3f);
    sh = be[c] - mean * sc;
  }
  sum[c] = sc; sq[c] = sh;
}

// ---------------- BN apply (+optional ELU, optional f32 out) ----------------
__global__ void k_bn_elu(const bf16_t* __restrict__ pre, const float* __restrict__ sc,
                         const float* __restrict__ sh, bf16_t* __restrict__ outb,
                         float* __restrict__ outf, int Nvalid, int Npad, int elu)
{
  const int  ng    = Npad >> 3;
  const long total = (long)B_ROWS * ng;
  for (long idx = (long)blockIdx.x * blockDim.x + threadIdx.x; idx < total;
       idx += (long)gridDim.x * blockDim.x) {
    const int r = (int)(idx / ng);
    const int c = (int)(idx % ng) * 8;
    bf16x8 o;
#pragma unroll
    for (int j = 0; j < 8; ++j) o[j] = (bf16_t)0.f;
    if (c < Nvalid) {                   // Nvalid % 8 == 0 -> group fully valid
      bf16x8 x = *(const bf16x8*)(pre + (size_t)r * Npad + c);
      f32x4 y0, y1;
#pragma unroll
      for (int j = 0; j < 8; ++j) {
        float v = (float)x[j] * sc[c + j] + sh[c + j];
        if (elu) v = v > 0.f ? v : expm1f(v);
        if (j < 4) y0[j] = v; else y1[j - 4] = v;
        o[j] = (bf16_t)v;
      }
      if (outf) {
        float* p = outf + (size_t)r * Nvalid + c;
        *(f32x4*)p       = y0;
        *(f32x4*)(p + 4) = y1;
      }
    }
    *(bf16x8*)(outb + (size_t)r * Npad + c) = o;
  }
}

// ---------------- reparametrize: mu/logvar/z f32 out + z bf16 (padded) ----------------
__global__ void k_reparam(const bf16_t* __restrict__ p, const float* __restrict__ sc,
                          const float* __restrict__ sh, const float* __restrict__ eps,
                          float* __restrict__ z, float* __restrict__ mu,
                          float* __restrict__ lv, bf16_t* __restrict__ zb)
{
  const long total = (long)B_ROWS * (LTP / 4);
  for (long idx = (long)blockIdx.x * blockDim.x + threadIdx.x; idx < total;
       idx += (long)gridDim.x * blockDim.x) {
    const int r = (int)(idx / (LTP / 4));
    const int j = (int)(idx % (LTP / 4)) * 4;
    if (j < LT) {                       // LT % 4 == 0
      bf16x4 pm = *(const bf16x4*)(p + (size_t)r * H2P + j);
      bf16x4 pl = *(const bf16x4*)(p + (size_t)r * H2P + LT + j);
      f32x4  e  = *(const f32x4*)(eps + (size_t)r * LT + j);
      f32x4 mv, lvv, zv; bf16x4 z4;
#pragma unroll
      for (int t = 0; t < 4; ++t) {
        float m_ = (float)pm[t] * sc[j + t] + sh[j + t];
        float l_ = (float)pl[t] * sc[LT + j + t] + sh[LT + j + t];
        float zz = fmaf(expf(l_ * 0.5f), e[t], m_);
        mv[t] = m_; lvv[t] = l_; zv[t] = zz; z4[t] = (bf16_t)zz;
      }
      *(f32x4*)(mu + (size_t)r * LT + j) = mv;
      *(f32x4*)(lv + (size_t)r * LT + j) = lvv;
      *(f32x4*)(z  + (size_t)r * LT + j) = zv;
      *(bf16x4*)(zb + (size_t)r * LTP + j) = z4;
    } else {
      bf16x4 z4;
#pragma unroll
      for (int t = 0; t < 4; ++t) z4[t] = (bf16_t)0.f;
      *(bf16x4*)(zb + (size_t)r * LTP + j) = z4;
    }
  }
}

// ---------------- host ----------------
extern "C" void kernel_launch(void* const* d_in, const int* in_sizes, int n_in,
                              void* d_out, int out_size, void* d_ws, size_t ws_size,
                              hipStream_t stream)
{
  const float* x     = (const float*)d_in[0];
  const float* eps   = (const float*)d_in[1];
  const float* mask1 = (const float*)d_in[2];
  const float* mask2 = (const float*)d_in[3];
  const float* maskd = (const float*)d_in[4];
  const float* maskm = (const float*)d_in[5];
  const float* W1    = (const float*)d_in[6];
  // b1 (d_in[7]) cancels in BN (mean subtraction) -> unused
  const float* g1    = (const float*)d_in[8];
  const float* be1   = (const float*)d_in[9];
  const float* W2    = (const float*)d_in[10];
  // b2 (d_in[11]) cancels in BN
  const float* g2    = (const float*)d_in[12];
  const float* be2   = (const float*)d_in[13];
  const float* Wd    = (const float*)d_in[14];
  // bd (d_in[15]) cancels in BN
  const float* gd    = (const float*)d_in[16];
  const float* bed   = (const float*)d_in[17];
  const float* Wm    = (const float*)d_in[18];
  float* out = (float*)d_out;
  char*  ws  = (char*)d_ws;

  // workspace layout (aliased where lifetimes are disjoint)
  size_t off = 0;
  auto alloc = [&](size_t bytes) { size_t o = off; off += (bytes + 255) & ~(size_t)255; return o; };
  const size_t XBF  = alloc((size_t)B_ROWS * GENP * 2);  // x bf16; later mo_bf16
  const size_t W1M  = alloc((size_t)H1P * GENP * 2);     // W1 masked; later p_pre
  const size_t W2M  = alloc((size_t)H2P * H1P * 2);
  const size_t WDM  = alloc((size_t)H1P * LTP * 2);
  const size_t WMM  = alloc((size_t)GENP * H1P * 2);
  const size_t HPRE = alloc((size_t)B_ROWS * H1P * 2);   // h_pre; later d_pre
  const size_t HBF  = alloc((size_t)B_ROWS * H1P * 2);   // h bf16; later z bf16
  const size_t STAT = alloc((size_t)(H1P + H2P + H1P) * 2 * sizeof(float));
  if (ws_size < off) {
    fprintf(stderr, "kernel_launch: workspace too small: need %zu have %zu\n", off, ws_size);
    return;
  }

  bf16_t* xb   = (bf16_t*)(ws + XBF);
  bf16_t* w1m  = (bf16_t*)(ws + W1M);
  bf16_t* w2m  = (bf16_t*)(ws + W2M);
  bf16_t* wdm  = (bf16_t*)(ws + WDM);
  bf16_t* wmm  = (bf16_t*)(ws + WMM);
  bf16_t* hpre = (bf16_t*)(ws + HPRE);
  bf16_t* hbf  = (bf16_t*)(ws + HBF);
  bf16_t* ppre = (bf16_t*)(ws + W1M);   // alias: W1 masked dead after GEMM1
  bf16_t* zbf  = (bf16_t*)(ws + HBF);   // alias: h bf16 dead after GEMM2
  bf16_t* dpre = (bf16_t*)(ws + HPRE);  // alias: h_pre dead after BN1 apply
  bf16_t* mobf = (bf16_t*)(ws + XBF);   // alias: x bf16 dead after GEMM1

  float* s1 = (float*)(ws + STAT);
  float* q1 = s1 + H1P;
  float* s2 = q1 + H1P;
  float* q2 = s2 + H2P;
  float* sd = q2 + H2P;
  float* qd = sd + H1P;

  float* o_recon = out;
  float* o_z     = o_recon + (size_t)B_ROWS * GEN;
  float* o_mo    = o_z     + (size_t)B_ROWS * LT;
  float* o_mu    = o_mo    + (size_t)B_ROWS * H1;
  float* o_lv    = o_mu    + (size_t)B_ROWS * LT;

  hipMemsetAsync(ws + STAT, 0, (size_t)(H1P + H2P + H1P) * 2 * sizeof(float), stream);

  // prep: cast/mask to bf16, zero-padded
  k_prep<<<2048, 256, 0, stream>>>(x,  nullptr, xb,  B_ROWS, GEN, B_ROWS, GENP);
  k_prep<<<2048, 256, 0, stream>>>(W1, mask1,   w1m, H1,  GEN, H1P,  GENP);
  k_prep<<<2048, 256, 0, stream>>>(W2, mask2,   w2m, H2,  H1,  H2P,  H1P);
  k_prep<<<2048, 256, 0, stream>>>(Wd, maskd,   wdm, H1,  LT,  H1P,  LTP);
  k_prep<<<2048, 256, 0, stream>>>(Wm, maskm,   wmm, GEN, H1,  GENP, H1P);

  // encoder L1: h_pre = x @ W1m^T  (+ batch stats)  [256^2 8-phase counted-vmcnt]
  gemm256<0><<<dim3(H1P / 256, B_ROWS / 256), 512, 0, stream>>>(
      xb, w1m, GENP, hpre, H1P, s1, q1, nullptr, 0);
  k_finalize<<<(H1P + 255) / 256, 256, 0, stream>>>(s1, q1, g1, be1, H1, H1P);
  k_bn_elu<<<2048, 256, 0, stream>>>(hpre, s1, q1, hbf, nullptr, H1, H1P, 1);

  // encoder L2: p_pre = h @ W2m^T (+ stats), then reparametrize  [128^2]
  gemm_bt<0><<<dim3(H2P / 128, B_ROWS / 128), 256, 0, stream>>>(
      hbf, w2m, H1P, ppre, H2P, s2, q2, nullptr, 0);
  k_finalize<<<(H2P + 255) / 256, 256, 0, stream>>>(s2, q2, g2, be2, H2, H2P);
  k_reparam<<<2048, 256, 0, stream>>>(ppre, s2, q2, eps, o_z, o_mu, o_lv, zbf);

  // decoder: d_pre = z @ Wdm^T (+ stats), BN+ELU -> module_outputs  [128^2]
  gemm_bt<0><<<dim3(H1P / 128, B_ROWS / 128), 256, 0, stream>>>(
      zbf, wdm, LTP, dpre, H1P, sd, qd, nullptr, 0);
  k_finalize<<<(H1P + 255) / 256, 256, 0, stream>>>(sd, qd, gd, bed, H1, H1P);
  k_bn_elu<<<2048, 256, 0, stream>>>(dpre, sd, qd, mobf, o_mo, H1, H1P, 1);

  // merger: global_recon = mo @ Wmm^T (f32 out, no BN)  [256^2 8-phase counted-vmcnt]
  gemm256<1><<<dim3(GENP / 256, B_ROWS / 256), 512, 0, stream>>>(
      mobf, wmm, H1P, nullptr, 0, nullptr, nullptr, o_recon, GEN);
}